// Round 3
// baseline (892.827 us; speedup 1.0000x reference)
//
#include <hip/hip_runtime.h>
#include <math.h>

#define N_NODES 50000
#define N_EDGES 160000
#define NB 32
#define C1N 25000
#define C2N 12500

// ---- workspace layout (in floats) ----
#define OFF_AGG1 0
#define SZ_AGG1 (N_NODES*32)
#define OFF_X2   (OFF_AGG1+SZ_AGG1)
#define SZ_X2    (C1N*32)
#define OFF_AGG2 (OFF_X2+SZ_X2)
#define SZ_AGG2  (C1N*64)
#define OFF_X4   (OFF_AGG2+SZ_AGG2)
#define SZ_X4    (C2N*64)
#define NEG_TOTAL (OFF_X4+SZ_X4)            // filled with -inf
#define OFF_P2S  NEG_TOTAL                  // pos2 sums  C1*2
#define OFF_CNT1 (OFF_P2S + C1N*2)          // counts     C1
#define OFF_GSUM (OFF_CNT1 + C1N)           // B*64
#define OFF_GCNT (OFF_GSUM + NB*64)         // B
#define OFF_CMAX (OFF_GCNT + NB)            // 1 (+3 pad)
#define OFF_B2I  (OFF_CMAX + 4)             // batch2 int C1
#define OFF_B3I  (OFF_B2I + C1N)            // batch3 int C2
#define ZERO_END (OFF_B3I + C2N)            // zero-filled up to here
#define OFF_POS2 (ZERO_END)                 // C1*2
#define OFF_ES   (OFF_POS2 + C1N*2)         // e2src int E
#define OFF_ED   (OFF_ES + N_EDGES)         // e2dst int E
#define OFF_CART (OFF_ED + N_EDGES)         // E*2

#define KTOT 832
#define KC 16

__device__ __forceinline__ void atomicMaxFloat(float* addr, float v) {
    if (v >= 0.0f) atomicMax((int*)addr, __float_as_int(v + 0.0f)); // +0.0 canonicalizes -0
    else           atomicMin((unsigned int*)addr, __float_as_uint(v));
}
__device__ __forceinline__ float eluf(float v) { return v > 0.0f ? v : expm1f(v); }

__global__ void k_init(float* ws) {
    int i = blockIdx.x*256 + threadIdx.x;
    if (i < ZERO_END) ws[i] = (i < NEG_TOTAL) ? -__builtin_inff() : 0.0f;
}

__global__ void k_pool1_aux(const float* __restrict__ pos, const int* __restrict__ batch,
                            const int* __restrict__ cl1, float* ws) {
    int n = blockIdx.x*256 + threadIdx.x;
    if (n >= N_NODES) return;
    int c = cl1[n];
    atomicAdd(&ws[OFF_P2S + c*2],     pos[n*2]);
    atomicAdd(&ws[OFF_P2S + c*2 + 1], pos[n*2+1]);
    atomicAdd(&ws[OFF_CNT1 + c], 1.0f);
    atomicMax((int*)(ws+OFF_B2I) + c, batch[n]);
}

// ---- conv1: fused edge-MLP + per-edge matvec as [64e x 832k] @ [832k x 32o] ----
__global__ __launch_bounds__(256) void k_conv1_edge(
    const float* __restrict__ x, const float* __restrict__ ea,
    const int* __restrict__ eidx, const float* __restrict__ w1,
    const float* __restrict__ b1, const float* __restrict__ w2,
    const float* __restrict__ b2, float* __restrict__ agg)
{
    __shared__ int src_s[64], dst_s[64];
    __shared__ float r_s[64*26];
    __shared__ float xs_s[64*32];
    __shared__ __align__(16) float K_s[64*KC];
    __shared__ __align__(16) float W_s[32*20];
    int tid = threadIdx.x;
    int e0 = blockIdx.x*64;
    if (tid < 64) { src_s[tid] = eidx[e0+tid]; dst_s[tid] = eidx[N_EDGES + e0 + tid]; }
    __syncthreads();
    for (int idx = tid; idx < 64*25; idx += 256) {
        int e = idx / 25, h = idx - e*25;
        float a0 = ea[(e0+e)*2], a1 = ea[(e0+e)*2+1];
        float v = a0*w1[h] + a1*w1[25+h] + b1[h];
        r_s[e*26+h] = fmaxf(v, 0.0f);
    }
    for (int idx = tid; idx < 64*32; idx += 256) {
        int e = idx >> 5, i = idx & 31;
        xs_s[idx] = x[src_s[e]*32 + i];
    }
    __syncthreads();
    int o2 = tid & 15, eq = tid >> 4;
    float acc[4][2] = {};
    for (int kb = 0; kb < KTOT; kb += KC) {
        #pragma unroll
        for (int p = 0; p < 2; ++p) {
            int idx = tid + p*256;
            int k = idx >> 5, o = idx & 31, kk = kb + k;
            float wv = (kk < 800) ? w2[(kk>>5)*1024 + (kk&31)*32 + o] : b2[(kk-800)*32 + o];
            W_s[o*20 + k] = wv;
        }
        #pragma unroll
        for (int p = 0; p < 4; ++p) {
            int idx = tid + p*256;
            int e = idx >> 4, kl = idx & 15, kk = kb + kl;
            float kv = (kk < 800) ? r_s[e*26 + (kk>>5)] * xs_s[e*32 + (kk&31)]
                                  : xs_s[e*32 + (kk-800)];
            K_s[e*KC + kl] = kv;
        }
        __syncthreads();
        #pragma unroll
        for (int k4 = 0; k4 < KC; k4 += 4) {
            float4 wa = *(const float4*)&W_s[o2*20 + k4];
            float4 wb = *(const float4*)&W_s[(o2+16)*20 + k4];
            #pragma unroll
            for (int j = 0; j < 4; ++j) {
                float4 kv = *(const float4*)&K_s[(eq*4+j)*KC + k4];
                acc[j][0] += kv.x*wa.x + kv.y*wa.y + kv.z*wa.z + kv.w*wa.w;
                acc[j][1] += kv.x*wb.x + kv.y*wb.y + kv.z*wb.z + kv.w*wb.w;
            }
        }
        __syncthreads();
    }
    #pragma unroll
    for (int j = 0; j < 4; ++j) {
        int d = dst_s[eq*4+j];
        atomicMaxFloat(&agg[d*32 + o2],      acc[j][0]);
        atomicMaxFloat(&agg[d*32 + o2 + 16], acc[j][1]);
    }
}

__global__ void k_conv1_final(const float* __restrict__ x, const float* __restrict__ root1,
                              const float* __restrict__ bias1, const int* __restrict__ cl1,
                              float* ws) {
    int idx = blockIdx.x*256 + threadIdx.x;
    if (idx >= N_NODES*32) return;
    int n = idx >> 5, o = idx & 31;
    float v = ws[OFF_AGG1 + idx];
    if (v == -__builtin_inff()) v = 0.0f;
    float acc = bias1[o];
    const float* xr = x + n*32;
    #pragma unroll
    for (int i = 0; i < 32; ++i) acc += xr[i]*root1[i*32+o];
    v = eluf(v + acc);
    atomicMaxFloat(&ws[OFF_X2 + cl1[n]*32 + o], v);
}

__global__ void k_pos2div(float* ws) {
    int i = blockIdx.x*256 + threadIdx.x;
    if (i >= C1N*2) return;
    int c = i >> 1;
    ws[OFF_POS2 + i] = ws[OFF_P2S + i] / fmaxf(ws[OFF_CNT1 + c], 1.0f);
}

__global__ void k_cart1(const int* __restrict__ eidx, const int* __restrict__ cl1,
                        float* ws) {
    int e = blockIdx.x*256 + threadIdx.x;
    float m = 0.0f;
    if (e < N_EDGES) {
        int s = cl1[eidx[e]], d = cl1[eidx[N_EDGES+e]];
        ((int*)(ws+OFF_ES))[e] = s;
        ((int*)(ws+OFF_ED))[e] = d;
        float cx = ws[OFF_POS2 + d*2]     - ws[OFF_POS2 + s*2];
        float cy = ws[OFF_POS2 + d*2 + 1] - ws[OFF_POS2 + s*2 + 1];
        ws[OFF_CART + e*2] = cx; ws[OFF_CART + e*2 + 1] = cy;
        m = fmaxf(fabsf(cx), fabsf(cy));
    }
    #pragma unroll
    for (int off = 32; off; off >>= 1) m = fmaxf(m, __shfl_xor(m, off));
    if ((threadIdx.x & 63) == 0) atomicMax((int*)(ws+OFF_CMAX), __float_as_int(m));
}

// ---- conv2: [32e x 832k] @ [832k x 64o] ----
__global__ __launch_bounds__(256) void k_conv2_edge(
    const float* __restrict__ w1, const float* __restrict__ b1,
    const float* __restrict__ w2, const float* __restrict__ b2, float* ws)
{
    __shared__ int src_s[32], dst_s[32];
    __shared__ float r_s[32*26];
    __shared__ float xs_s[32*32];
    __shared__ __align__(16) float K_s[32*KC];
    __shared__ __align__(16) float W_s[64*20];
    const float* x2   = ws + OFF_X2;
    const int*   e2s  = (const int*)(ws + OFF_ES);
    const int*   e2d  = (const int*)(ws + OFF_ED);
    const float* cart = ws + OFF_CART;
    float inv2m = 0.5f / ws[OFF_CMAX];
    float* agg = ws + OFF_AGG2;
    int tid = threadIdx.x;
    int e0 = blockIdx.x*32;
    if (tid < 32) { src_s[tid] = e2s[e0+tid]; dst_s[tid] = e2d[e0+tid]; }
    __syncthreads();
    for (int idx = tid; idx < 32*25; idx += 256) {
        int e = idx / 25, h = idx - e*25;
        float a0 = cart[(e0+e)*2]*inv2m + 0.5f;
        float a1 = cart[(e0+e)*2+1]*inv2m + 0.5f;
        float v = a0*w1[h] + a1*w1[25+h] + b1[h];
        r_s[e*26+h] = fmaxf(v, 0.0f);
    }
    for (int idx = tid; idx < 32*32; idx += 256) {
        int e = idx >> 5, i = idx & 31;
        xs_s[idx] = x2[src_s[e]*32 + i];
    }
    __syncthreads();
    int o2 = tid & 31, eq = tid >> 5;
    float acc[4][2] = {};
    for (int kb = 0; kb < KTOT; kb += KC) {
        #pragma unroll
        for (int p = 0; p < 4; ++p) {
            int idx = tid + p*256;
            int k = idx >> 6, o = idx & 63, kk = kb + k;
            float wv = (kk < 800) ? w2[(kk>>5)*2048 + (kk&31)*64 + o] : b2[(kk-800)*64 + o];
            W_s[o*20 + k] = wv;
        }
        #pragma unroll
        for (int p = 0; p < 2; ++p) {
            int idx = tid + p*256;
            int e = idx >> 4, kl = idx & 15, kk = kb + kl;
            float kv = (kk < 800) ? r_s[e*26 + (kk>>5)] * xs_s[e*32 + (kk&31)]
                                  : xs_s[e*32 + (kk-800)];
            K_s[e*KC + kl] = kv;
        }
        __syncthreads();
        #pragma unroll
        for (int k4 = 0; k4 < KC; k4 += 4) {
            float4 wa = *(const float4*)&W_s[o2*20 + k4];
            float4 wb = *(const float4*)&W_s[(o2+32)*20 + k4];
            #pragma unroll
            for (int j = 0; j < 4; ++j) {
                float4 kv = *(const float4*)&K_s[(eq*4+j)*KC + k4];
                acc[j][0] += kv.x*wa.x + kv.y*wa.y + kv.z*wa.z + kv.w*wa.w;
                acc[j][1] += kv.x*wb.x + kv.y*wb.y + kv.z*wb.z + kv.w*wb.w;
            }
        }
        __syncthreads();
    }
    #pragma unroll
    for (int j = 0; j < 4; ++j) {
        int e = eq*4+j;
        if (src_s[e] != dst_s[e]) {
            int d = dst_s[e];
            atomicMaxFloat(&agg[d*64 + o2],      acc[j][0]);
            atomicMaxFloat(&agg[d*64 + o2 + 32], acc[j][1]);
        }
    }
}

__global__ void k_conv2_final(const float* __restrict__ root2, const float* __restrict__ bias2,
                              const int* __restrict__ cl2, float* ws) {
    int idx = blockIdx.x*256 + threadIdx.x;
    if (idx >= C1N*64) return;
    int c = idx >> 6, o = idx & 63;
    float v = ws[OFF_AGG2 + idx];
    if (v == -__builtin_inff()) v = 0.0f;
    float acc = bias2[o];
    #pragma unroll
    for (int i = 0; i < 32; ++i) acc += ws[OFF_X2 + c*32 + i]*root2[i*64+o];
    v = eluf(v + acc);
    int c2 = cl2[c];
    atomicMaxFloat(&ws[OFF_X4 + c2*64 + o], v);
    if (o == 0) atomicMax((int*)(ws+OFF_B3I) + c2, ((int*)(ws+OFF_B2I))[c]);
}

__global__ void k_gpool(float* ws) {
    int idx = blockIdx.x*256 + threadIdx.x;
    if (idx >= C2N*64) return;
    int c = idx >> 6, o = idx & 63;
    float v = ws[OFF_X4 + idx];
    if (v == -__builtin_inff()) v = 0.0f;
    int b = ((int*)(ws+OFF_B3I))[c];
    atomicAdd(&ws[OFF_GSUM + b*64 + o], v);
    if (o == 0) atomicAdd(&ws[OFF_GCNT + b], 1.0f);
}

__global__ __launch_bounds__(256) void k_head(
    const float* __restrict__ fc1w, const float* __restrict__ fc1b,
    const float* __restrict__ fc2w, const float* __restrict__ fc2b,
    const float* __restrict__ ws, float* __restrict__ out) {
    __shared__ float g_s[32*64], h_s[32*128], l_s[32*32];
    int tid = threadIdx.x;
    for (int idx = tid; idx < 32*64; idx += 256) {
        int b = idx >> 6;
        g_s[idx] = ws[OFF_GSUM + idx] / fmaxf(ws[OFF_GCNT + b], 1.0f);
    }
    __syncthreads();
    for (int idx = tid; idx < 32*128; idx += 256) {
        int b = idx >> 7, f = idx & 127;
        float a = fc1b[f];
        #pragma unroll 8
        for (int i = 0; i < 64; ++i) a += g_s[b*64+i]*fc1w[i*128+f];
        h_s[idx] = eluf(a);
    }
    __syncthreads();
    for (int idx = tid; idx < 32*32; idx += 256) {
        int b = idx >> 5, o = idx & 31;
        float a = fc2b[o];
        #pragma unroll 8
        for (int i = 0; i < 128; ++i) a += h_s[b*128+i]*fc2w[i*32+o];
        l_s[idx] = a;
    }
    __syncthreads();
    if (tid < 32) {
        int b = tid;
        float m = -__builtin_inff();
        for (int o = 0; o < 32; ++o) m = fmaxf(m, l_s[b*32+o]);
        float s = 0.0f;
        for (int o = 0; o < 32; ++o) s += expf(l_s[b*32+o]-m);
        float lg = logf(s);
        for (int o = 0; o < 32; ++o) out[b*32+o] = l_s[b*32+o]-m-lg;
    }
}

extern "C" void kernel_launch(void* const* d_in, const int* in_sizes, int n_in,
                              void* d_out, int out_size, void* d_ws, size_t ws_size,
                              hipStream_t stream) {
    const float* x    = (const float*)d_in[0];
    const float* pos  = (const float*)d_in[1];
    const float* ea   = (const float*)d_in[2];
    const int*   eidx = (const int*)  d_in[3];
    const int*   batch= (const int*)  d_in[4];
    const int*   cl1  = (const int*)  d_in[5];
    const int*   cl2  = (const int*)  d_in[6];
    const float* n1w1 = (const float*)d_in[7];
    const float* n1b1 = (const float*)d_in[8];
    const float* n1w2 = (const float*)d_in[9];
    const float* n1b2 = (const float*)d_in[10];
    const float* root1= (const float*)d_in[11];
    const float* bias1= (const float*)d_in[12];
    const float* n2w1 = (const float*)d_in[13];
    const float* n2b1 = (const float*)d_in[14];
    const float* n2w2 = (const float*)d_in[15];
    const float* n2b2 = (const float*)d_in[16];
    const float* root2= (const float*)d_in[17];
    const float* bias2= (const float*)d_in[18];
    const float* fc1w = (const float*)d_in[19];
    const float* fc1b = (const float*)d_in[20];
    const float* fc2w = (const float*)d_in[21];
    const float* fc2b = (const float*)d_in[22];
    float* ws  = (float*)d_ws;
    float* out = (float*)d_out;

    hipLaunchKernelGGL(k_init, dim3((ZERO_END+255)/256), dim3(256), 0, stream, ws);
    hipLaunchKernelGGL(k_pool1_aux, dim3((N_NODES+255)/256), dim3(256), 0, stream,
                       pos, batch, cl1, ws);
    hipLaunchKernelGGL(k_conv1_edge, dim3(N_EDGES/64), dim3(256), 0, stream,
                       x, ea, eidx, n1w1, n1b1, n1w2, n1b2, ws + OFF_AGG1);
    hipLaunchKernelGGL(k_conv1_final, dim3((N_NODES*32+255)/256), dim3(256), 0, stream,
                       x, root1, bias1, cl1, ws);
    hipLaunchKernelGGL(k_pos2div, dim3((C1N*2+255)/256), dim3(256), 0, stream, ws);
    hipLaunchKernelGGL(k_cart1, dim3((N_EDGES+255)/256), dim3(256), 0, stream,
                       eidx, cl1, ws);
    hipLaunchKernelGGL(k_conv2_edge, dim3(N_EDGES/32), dim3(256), 0, stream,
                       n2w1, n2b1, n2w2, n2b2, ws);
    hipLaunchKernelGGL(k_conv2_final, dim3((C1N*64+255)/256), dim3(256), 0, stream,
                       root2, bias2, cl2, ws);
    hipLaunchKernelGGL(k_gpool, dim3((C2N*64+255)/256), dim3(256), 0, stream, ws);
    hipLaunchKernelGGL(k_head, dim3(1), dim3(256), 0, stream,
                       fc1w, fc1b, fc2w, fc2b, ws, out);
}